// Round 18
// baseline (1299.376 us; speedup 1.0000x reference)
//
#include <hip/hip_runtime.h>

#define BB 8
#define NN 8192
#define SS 1024
#define KK 32
#define NPIX (BB*SS*KK)   // 262144
#define R2C 0.04f
#define EPS 1e-5f

#define FT 1024           // fps threads (16 waves)
#define FW (FT/64)        // 16 waves
#define PPT (NN/FT)       // 8 points per thread
#define NCELL 4096        // 16^3 morton cells
#define TBLK 64           // transpose blocks fused into fps launch

#define LT 512            // layer threads (8 waves)
#define LB 512            // layer blocks (2 per CU)

typedef float v2f __attribute__((ext_vector_type(2)));

// ---------- ws layout (bytes) ----------
#define OFF_IDX      0u
#define OFF_NEWXYZ   (OFF_IDX + BB*SS*4)
#define OFF_GIDX     (OFF_NEWXYZ + BB*SS*3*4)
#define OFF_XYZN     (OFF_GIDX + BB*SS*KK*4)
#define OFF_PTSN     (OFF_XYZN + BB*NN*3*4)
#define OFF_Y0       (OFF_PTSN + BB*NN*64*4)
#define OFF_Y1       (OFF_Y0 + NPIX*64*2)
#define OFF_MAXMIN   (OFF_Y1 + NPIX*64*2)       // 2 planes of BB*128*SS floats
#define OFF_P0       (OFF_MAXMIN + BB*SS*128*2*4)
#define OFF_P1       (OFF_P0 + LB*128*4)
#define OFF_P2       (OFF_P1 + LB*128*4)

__device__ __forceinline__ unsigned short f2bf(float x){
    unsigned u = __float_as_uint(x);
    unsigned r = (u + 0x7FFFu + ((u >> 16) & 1u)) >> 16;
    return (unsigned short)r;
}
__device__ __forceinline__ float bf2f(unsigned h){
    return __uint_as_float(h << 16);
}
__device__ __forceinline__ float sqdist3(float dx, float dy, float dz){
    // numpy order, no fma contraction: ((dx*dx)+(dy*dy))+(dz*dz)
    return __fadd_rn(__fadd_rn(__fmul_rn(dx,dx), __fmul_rn(dy,dy)), __fmul_rn(dz,dz));
}
__device__ __forceinline__ int spread4(int v){ // bits 0..3 -> 0,3,6,9
    return (v&1) | ((v&2)<<2) | ((v&4)<<4) | ((v&8)<<6);
}

// ---- DPP helpers ----
template<int CTRL>
__device__ __forceinline__ float dppf_max(float v){
    int o = __builtin_amdgcn_update_dpp(__float_as_int(v), __float_as_int(v), CTRL, 0xf, 0xf, false);
    return fmaxf(v, __int_as_float(o));
}
template<int CTRL>
__device__ __forceinline__ float dppf_min(float v){
    int o = __builtin_amdgcn_update_dpp(__float_as_int(v), __float_as_int(v), CTRL, 0xf, 0xf, false);
    return fminf(v, __int_as_float(o));
}
template<int CTRL>
__device__ __forceinline__ unsigned dppu_min(unsigned v){
    unsigned o = (unsigned)__builtin_amdgcn_update_dpp((int)v, (int)v, CTRL, 0xf, 0xf, false);
    return min(v, o);
}
template<int CTRL>
__device__ __forceinline__ float dpp_sum_step(float v){
    int o = __builtin_amdgcn_update_dpp(0, __float_as_int(v), CTRL, 0xf, 0xf, true);
    return v + __int_as_float(o);
}
__device__ __forceinline__ float wave_sum_f32(float v){   // lane63 = sum over 64
    v = dpp_sum_step<0x111>(v); v = dpp_sum_step<0x112>(v);
    v = dpp_sum_step<0x114>(v); v = dpp_sum_step<0x118>(v);
    v = dpp_sum_step<0x142>(v); v = dpp_sum_step<0x143>(v);
    return v;
}
__device__ __forceinline__ float grp32_max(float v){      // lanes 31/63 = group max
    v = dppf_max<0x111>(v); v = dppf_max<0x112>(v);
    v = dppf_max<0x114>(v); v = dppf_max<0x118>(v);
    v = dppf_max<0x142>(v);
    return v;
}
__device__ __forceinline__ float grp32_min(float v){      // lanes 31/63 = group min
    v = dppf_min<0x111>(v); v = dppf_min<0x112>(v);
    v = dppf_min<0x114>(v); v = dppf_min<0x118>(v);
    v = dppf_min<0x142>(v);
    return v;
}
__device__ __forceinline__ float wave_max_f32(float v){   // lane63 = max over 64
    v = dppf_max<0x111>(v); v = dppf_max<0x112>(v);
    v = dppf_max<0x114>(v); v = dppf_max<0x118>(v);
    v = dppf_max<0x142>(v); v = dppf_max<0x143>(v);
    return v;
}
__device__ __forceinline__ unsigned wave_min_u32(unsigned v){ // lane63 = min over 64
    v = dppu_min<0x111>(v); v = dppu_min<0x112>(v);
    v = dppu_min<0x114>(v); v = dppu_min<0x118>(v);
    v = dppu_min<0x142>(v); v = dppu_min<0x143>(v);
    return v;
}

// ---------- FPS (blocks 0..7) + fused transpose (blocks 8..71) ----------
__global__ __launch_bounds__(FT) void fps_kernel(const float* __restrict__ xyz,
                                                 const float* __restrict__ pts,
                                                 float* __restrict__ newxyz,
                                                 float* __restrict__ out,
                                                 float* __restrict__ xyz_n,
                                                 float* __restrict__ pts_n){
    __shared__ float sxyz[NN * 3];               // interleaved x,y,z per point
    __shared__ int   si[NN];                     // sorted -> original idx
    __shared__ int   hist[NCELL];                // sort workspace, then winner history
    __shared__ int   waveTot[FW];
    __shared__ unsigned long long cells[SS];     // one winner cell per iteration
    int tid = threadIdx.x;

    if (blockIdx.x >= 8){
        // transpose path: xyz (B,3,N)->(B,N,3), pts (B,64,N)->(B,N,64)
        int gid = (blockIdx.x - 8) * FT + tid;   // 65536 = B*N
        int b = gid >> 13, i = gid & (NN - 1);
        const float* xb = xyz + (size_t)b * 3 * NN;
        float x = xb[i], y = xb[NN + i], z = xb[2 * NN + i];
        float* xd = xyz_n + ((size_t)b * NN + i) * 3;
        xd[0] = x; xd[1] = y; xd[2] = z;
        const float* pb = pts + (size_t)b * 64 * NN + i;
        float4* pd = (float4*)(pts_n + ((size_t)b * NN + i) * 64);
#pragma unroll
        for (int q = 0; q < 16; ++q){
            float4 v;
            v.x = pb[(q*4+0)*NN]; v.y = pb[(q*4+1)*NN];
            v.z = pb[(q*4+2)*NN]; v.w = pb[(q*4+3)*NN];
            pd[q] = v;
        }
        return;
    }

    int b = blockIdx.x;
    int wave = tid >> 6, lane = tid & 63;
    const float* xb = xyz + (size_t)b * 3 * NN;

    // ---- load coords to LDS + morton cells ----
    int cell[PPT];
#pragma unroll
    for (int j = 0; j < PPT; ++j){
        int i = tid + j * FT;
        float x = xb[i], y = xb[NN + i], z = xb[2*NN + i];
        sxyz[i*3]   = x; sxyz[i*3+1] = y; sxyz[i*3+2] = z;
        int cx = min(15, max(0, (int)(x * 16.f)));
        int cy = min(15, max(0, (int)(y * 16.f)));
        int cz = min(15, max(0, (int)(z * 16.f)));
        cell[j] = spread4(cx) | (spread4(cy) << 1) | (spread4(cz) << 2);
    }
#pragma unroll
    for (int k = 0; k < NCELL/FT; ++k) hist[tid * (NCELL/FT) + k] = 0;
    cells[tid] = 0ull;   // FT == SS == 1024
    __syncthreads();
#pragma unroll
    for (int j = 0; j < PPT; ++j) atomicAdd(&hist[cell[j]], 1);
    __syncthreads();
    // ---- exclusive scan over 4096 cells ----
    {
        int base0 = tid * (NCELL/FT);
        int sum4 = 0;
#pragma unroll
        for (int k = 0; k < NCELL/FT; ++k) sum4 += hist[base0 + k];
        int s = sum4;
#pragma unroll
        for (int m = 1; m < 64; m <<= 1){
            int v = __shfl_up(s, m);
            if (lane >= m) s += v;
        }
        if (lane == 63) waveTot[wave] = s;
        __syncthreads();
        int wbase = 0;
#pragma unroll
        for (int w2 = 0; w2 < FW; ++w2) if (w2 < wave) wbase += waveTot[w2];
        int run = wbase + s - sum4;
#pragma unroll
        for (int k = 0; k < NCELL/FT; ++k){
            int h = hist[base0 + k];
            hist[base0 + k] = run;
            run += h;
        }
    }
    __syncthreads();
#pragma unroll
    for (int j = 0; j < PPT; ++j){
        int pos = atomicAdd(&hist[cell[j]], 1);
        si[pos] = tid + j * FT;
    }
    __syncthreads();
    // ---- gather sorted chunk + bbox (packed v2f regs) ----
    v2f px[PPT/2], py[PPT/2], pz[PPT/2];
    float dist[PPT];
    int oi[PPT];
    float bxmin =  1e30f, bxmax = -1e30f;
    float bymin =  1e30f, bymax = -1e30f;
    float bzmin =  1e30f, bzmax = -1e30f;
#pragma unroll
    for (int j = 0; j < PPT; ++j){
        int g = si[tid * PPT + j];
        oi[j] = g;
        float x = sxyz[g*3], y = sxyz[g*3+1], z = sxyz[g*3+2];
        px[j>>1][j&1] = x; py[j>>1][j&1] = y; pz[j>>1][j&1] = z;
        bxmin = fminf(bxmin, x); bxmax = fmaxf(bxmax, x);
        bymin = fminf(bymin, y); bymax = fmaxf(bymax, y);
        bzmin = fminf(bzmin, z); bzmax = fmaxf(bzmax, z);
        dist[j] = __int_as_float(0x7f800000); // +inf
    }
    __syncthreads();   // hist[] now dead -> reused as winner history

    float tmax = __int_as_float(0x7f800000);
    int   bidx = 0;
    unsigned long long wkey = 0ull;
    int w = 0;
    for (int t = 0; t < SS; ++t){
        if (tid == 0) hist[t] = w;     // reference: idx[t] = CURRENT point
        int w3 = w * 3;
        float lx = sxyz[w3], ly = sxyz[w3+1], lz = sxyz[w3+2];
        float cdx = __fsub_rn(lx, fminf(fmaxf(lx, bxmin), bxmax));
        float cdy = __fsub_rn(ly, fminf(fmaxf(ly, bymin), bymax));
        float cdz = __fsub_rn(lz, fminf(fmaxf(lz, bzmin), bzmax));
        float d_bb = sqdist3(cdx, cdy, cdz);
        bool active = d_bb < tmax;
        unsigned long long bal = __ballot(active);
        if (bal){
            if (active){
                {
#pragma clang fp contract(off)
                    v2f lx2 = {lx, lx}, ly2 = {ly, ly}, lz2 = {lz, lz};
#pragma unroll
                    for (int p = 0; p < PPT/2; ++p){
                        v2f dx = px[p] - lx2;
                        v2f dy = py[p] - ly2;
                        v2f dz = pz[p] - lz2;
                        v2f d  = ((dx*dx) + (dy*dy)) + (dz*dz);  // numpy order
                        dist[2*p]   = fminf(dist[2*p],   d[0]);
                        dist[2*p+1] = fminf(dist[2*p+1], d[1]);
                    }
                }
                float m0 = fmaxf(dist[0], dist[1]);
                float m1 = fmaxf(dist[2], dist[3]);
                float m2 = fmaxf(dist[4], dist[5]);
                float m3 = fmaxf(dist[6], dist[7]);
                m0 = fmaxf(m0, m1); m2 = fmaxf(m2, m3);
                float maxd = fmaxf(m0, m2);
                int bo = 0x7fffffff;
#pragma unroll
                for (int j = 0; j < PPT; ++j)
                    if (dist[j] == maxd) bo = min(bo, oi[j]);
                tmax = maxd; bidx = bo;
            }
            // two-phase reduce: f32 max, then u32 min-index among maxima
            float m = wave_max_f32(tmax);
            float sm = __int_as_float(__builtin_amdgcn_readlane(__float_as_int(m), 63));
            unsigned cand = (tmax == sm) ? (unsigned)bidx : 0xFFFFFFFFu;
            cand = wave_min_u32(cand);
            unsigned sidx = (unsigned)__builtin_amdgcn_readlane((int)cand, 63);
            wkey = ((unsigned long long)__float_as_uint(sm) << 32) | (unsigned)(~sidx);
        }
        if (lane == 63) atomicMax(&cells[t], wkey);
        __syncthreads();
        w = (int)(~(unsigned)cells[t]);
    }
    __syncthreads();
    // ---- coalesced writeback from history ----
    for (int t2 = tid; t2 < SS; t2 += FT){
        int hw = hist[t2] * 3;
        float x = sxyz[hw], y = sxyz[hw+1], z = sxyz[hw+2];
        out[(size_t)b * 3 * SS + t2]          = x;
        out[(size_t)b * 3 * SS + SS + t2]     = y;
        out[(size_t)b * 3 * SS + 2*SS + t2]   = z;
        float* nw = newxyz + ((size_t)b * SS + t2) * 3;
        nw[0] = x; nw[1] = y; nw[2] = z;
    }
}

// ---------- layer0: in-block ball query + gather(streamed) + 67->64 matmul + stats ----------
__global__ __launch_bounds__(LT) void l0_kernel(const float* __restrict__ xyz,
                                                const float* __restrict__ pts_n,
                                                const float* __restrict__ xyz_n,
                                                const float* __restrict__ newxyz,
                                                const float* __restrict__ W0,
                                                const float* __restrict__ b0,
                                                uint4* __restrict__ y0,
                                                float* __restrict__ part0){
    __shared__ float lsum[8][64][2];    // 4 KB
    __shared__ int   gq[16][KK];        // 2 KB: this block's 16 samples
    int tid = threadIdx.x;
    int pixel = blockIdx.x * LT + tid;      // 512 blocks
    int sample = pixel >> 5;
    int b = sample >> 10;
    int wave = tid >> 6, lane = tid & 63;

    // ---- phase A: ball query for this block's 16 samples (wave w -> samples 2w, 2w+1) ----
    {
        const float* xb = xyz + (size_t)b * 3 * NN;
#pragma unroll
        for (int s2 = 0; s2 < 2; ++s2){
            int ls = wave * 2 + s2;                    // local sample 0..15
            int smp = blockIdx.x * 16 + ls;
            const float* nw = newxyz + (size_t)smp * 3;
            float cx = nw[0], cy = nw[1], cz = nw[2];
            int total = 0, firstIdx = -1;
            for (int base = 0; base < NN; base += 64){
                int i = base + lane;
                float dx = __fsub_rn(cx, xb[i]);
                float dy = __fsub_rn(cy, xb[NN + i]);
                float dz = __fsub_rn(cz, xb[2*NN + i]);
                float d2 = sqdist3(dx, dy, dz);
                bool in = (d2 <= R2C);
                unsigned long long m = __ballot(in);
                int pos = total + __popcll(m & ((1ull << lane) - 1ull));
                if (in && pos < KK) gq[ls][pos] = i;
                if (firstIdx < 0 && m) firstIdx = base + (__ffsll((unsigned long long)m) - 1);
                total += __popcll(m);
                if (total >= KK) break;
            }
            if (total < KK){
                int f = (total > 0) ? firstIdx : (NN - 1);
                for (int p = total + lane; p < KK; p += 64) gq[ls][p] = f;
            }
        }
    }
    __syncthreads();

    // ---- phase B: gather + streamed matmul + stats ----
    int gi = gq[tid >> 5][tid & 31];
    float acc[64];
#pragma unroll
    for (int j = 0; j < 64; ++j) acc[j] = b0[j];
    {
        const float4* prow = (const float4*)(pts_n + ((size_t)b * NN + gi) * 64);
#pragma unroll
        for (int q = 0; q < 16; ++q){
            float4 v = prow[q];
            int c = q * 4;
#pragma unroll
            for (int j = 0; j < 64; ++j){
                acc[j] += v.x * W0[j*67 + c];
                acc[j] += v.y * W0[j*67 + c+1];
                acc[j] += v.z * W0[j*67 + c+2];
                acc[j] += v.w * W0[j*67 + c+3];
            }
        }
        const float* pr = xyz_n + ((size_t)b * NN + gi) * 3;
        const float* nw = newxyz + (size_t)sample * 3;
#pragma unroll
        for (int k = 0; k < 3; ++k){
            float fe = __fsub_rn(pr[k], nw[k]) / 0.2f;
#pragma unroll
            for (int j = 0; j < 64; ++j) acc[j] += fe * W0[j*67 + 64 + k];
        }
    }
#pragma unroll
    for (int j = 0; j < 64; ++j){
        float v = acc[j];
        float s1 = wave_sum_f32(v);
        float s2 = wave_sum_f32(v * v);
        if (lane == 63){ lsum[wave][j][0] = s1; lsum[wave][j][1] = s2; }
    }
    // pack + store
    uint4* yo = y0 + (size_t)pixel * 8;
#pragma unroll
    for (int oc = 0; oc < 8; ++oc){
        uint4 pk;
        pk.x = f2bf(acc[oc*8+0]) | ((unsigned)f2bf(acc[oc*8+1]) << 16);
        pk.y = f2bf(acc[oc*8+2]) | ((unsigned)f2bf(acc[oc*8+3]) << 16);
        pk.z = f2bf(acc[oc*8+4]) | ((unsigned)f2bf(acc[oc*8+5]) << 16);
        pk.w = f2bf(acc[oc*8+6]) | ((unsigned)f2bf(acc[oc*8+7]) << 16);
        yo[oc] = pk;
    }
    __syncthreads();
    if (tid < 128){
        float s = 0.f;
#pragma unroll
        for (int w2 = 0; w2 < 8; ++w2) s += lsum[w2][tid>>1][tid&1];
        part0[(size_t)blockIdx.x * 128 + tid] = s;
    }
}

// ---------- redundant per-block BN finalize (deterministic, from LB x 128 partials, 512 thr) ----------
__device__ __forceinline__ void fin_head128(const float* __restrict__ part,
                                            const float* __restrict__ g,
                                            const float* __restrict__ be,
                                            float* fs, float* scl, float* shf){
    int tid = threadIdx.x;               // 512
    int m = tid & 127, chunk = tid >> 7; // 4 chunks x 128 rows
    float s = 0.f;
    for (int r = chunk*128; r < chunk*128 + 128; ++r)
        s += part[(size_t)r * 128 + m];
    fs[tid] = s;
    __syncthreads();
    if (tid < 128){
        float t = fs[tid];
#pragma unroll
        for (int c = 1; c < 4; ++c) t += fs[c*128 + tid];
        fs[tid] = t;
    }
    __syncthreads();
    if (tid < 64){
        float s1 = fs[2*tid], s2 = fs[2*tid+1];
        float inv = 1.0f / (float)NPIX;
        float mu = s1 * inv;
        float var = s2 * inv - mu * mu;
        float sc = (1.0f / sqrtf(var + EPS)) * g[tid];
        scl[tid] = sc;
        shf[tid] = be[tid] - mu * sc;
    }
    __syncthreads();
}

// ---------- layer1: fin0 head + bn+relu + 64->64 matmul + stats ----------
__global__ __launch_bounds__(LT) void l1_kernel(const uint4* __restrict__ y0,
                                                const float* __restrict__ part0,
                                                const float* __restrict__ g0,
                                                const float* __restrict__ be0,
                                                const float* __restrict__ W1,
                                                const float* __restrict__ b1,
                                                uint4* __restrict__ y1,
                                                float* __restrict__ part1){
    __shared__ float lsum[8][64][2];    // 4 KB
    __shared__ float fs[LT];            // 2 KB
    __shared__ float scl[64], shf[64];
    int tid = threadIdx.x;
    int pixel = blockIdx.x * LT + tid;
    int wave = tid >> 6, lane = tid & 63;

    fin_head128(part0, g0, be0, fs, scl, shf);

    float x[64];
#pragma unroll
    for (int q = 0; q < 8; ++q){
        uint4 v = y0[(size_t)pixel * 8 + q];
        unsigned wv[4] = {v.x, v.y, v.z, v.w};
#pragma unroll
        for (int r = 0; r < 4; ++r){
            int c = q*8 + r*2;
            x[c]   = fmaxf(bf2f(wv[r] & 0xFFFFu) * scl[c]   + shf[c],   0.f);
            x[c+1] = fmaxf(bf2f(wv[r] >> 16)     * scl[c+1] + shf[c+1], 0.f);
        }
    }
#pragma unroll
    for (int oc = 0; oc < 8; ++oc){
        float acc[8];
#pragma unroll
        for (int j = 0; j < 8; ++j) acc[j] = b1[oc*8+j];
#pragma unroll
        for (int c = 0; c < 64; ++c){
            float fe = x[c];
#pragma unroll
            for (int j = 0; j < 8; ++j) acc[j] += fe * W1[(oc*8+j)*64 + c];
        }
        uint4 pk;
        unsigned us[8];
#pragma unroll
        for (int j = 0; j < 8; ++j){
            float v = acc[j];
            float s1 = wave_sum_f32(v);
            float s2 = wave_sum_f32(v * v);
            if (lane == 63){ lsum[wave][oc*8+j][0] = s1; lsum[wave][oc*8+j][1] = s2; }
            us[j] = f2bf(v);
        }
        pk.x = us[0] | (us[1] << 16);
        pk.y = us[2] | (us[3] << 16);
        pk.z = us[4] | (us[5] << 16);
        pk.w = us[6] | (us[7] << 16);
        y1[(size_t)pixel * 8 + oc] = pk;
    }
    __syncthreads();
    if (tid < 128){
        float s = 0.f;
#pragma unroll
        for (int w2 = 0; w2 < 8; ++w2) s += lsum[w2][tid>>1][tid&1];
        part1[(size_t)blockIdx.x * 128 + tid] = s;
    }
}

// ---------- layer2: fin1 head + bn+relu + 64->128 matmul + k-max/min + stats ----------
__global__ __launch_bounds__(LT) void l2_kernel(const uint4* __restrict__ y1,
                                                const float* __restrict__ part1,
                                                const float* __restrict__ g1,
                                                const float* __restrict__ be1,
                                                const float* __restrict__ W2,
                                                const float* __restrict__ b2,
                                                float* __restrict__ maxp,
                                                float* __restrict__ minp,
                                                float* __restrict__ part2){
    __shared__ float lsum[8][128][2];   // 8 KB
    __shared__ float fs[LT];
    __shared__ float scl[64], shf[64];
    int tid = threadIdx.x;
    int pixel = blockIdx.x * LT + tid;
    int sample = pixel >> 5;
    int sb = sample >> 10;              // batch
    int sl = sample & 1023;             // sample within batch
    int wave = tid >> 6, lane = tid & 63;

    fin_head128(part1, g1, be1, fs, scl, shf);

    float x[64];
#pragma unroll
    for (int q = 0; q < 8; ++q){
        uint4 v = y1[(size_t)pixel * 8 + q];
        unsigned wv[4] = {v.x, v.y, v.z, v.w};
#pragma unroll
        for (int r = 0; r < 4; ++r){
            int c = q*8 + r*2;
            x[c]   = fmaxf(bf2f(wv[r] & 0xFFFFu) * scl[c]   + shf[c],   0.f);
            x[c+1] = fmaxf(bf2f(wv[r] >> 16)     * scl[c+1] + shf[c+1], 0.f);
        }
    }
#pragma unroll
    for (int oc = 0; oc < 16; ++oc){
        float acc[8];
#pragma unroll
        for (int j = 0; j < 8; ++j) acc[j] = b2[oc*8+j];
#pragma unroll
        for (int c = 0; c < 64; ++c){
            float fe = x[c];
#pragma unroll
            for (int j = 0; j < 8; ++j) acc[j] += fe * W2[(oc*8+j)*64 + c];
        }
#pragma unroll
        for (int j = 0; j < 8; ++j){
            float v = acc[j];
            int ch = oc*8 + j;
            float mx = grp32_max(v);
            float mn = grp32_min(v);
            float s1 = wave_sum_f32(v);
            float s2 = wave_sum_f32(v * v);
            if (lane == 63){ lsum[wave][ch][0] = s1; lsum[wave][ch][1] = s2; }
            if ((tid & 31) == 31){
                size_t idx = ((size_t)sb * 128 + ch) * 1024 + sl;
                maxp[idx] = mx; minp[idx] = mn;
            }
        }
    }
    __syncthreads();
    if (tid < 256){
        float s = 0.f;
#pragma unroll
        for (int w2 = 0; w2 < 8; ++w2) s += lsum[w2][tid>>1][tid&1];
        part2[(size_t)blockIdx.x * 256 + tid] = s;
    }
}

// ---------- output: fin2 head + apply BN to max/min, relu, coalesced write ----------
__global__ __launch_bounds__(LT) void out_kernel(const float* __restrict__ maxp,
                                                 const float* __restrict__ minp,
                                                 const float* __restrict__ part2,
                                                 const float* __restrict__ g2,
                                                 const float* __restrict__ be2,
                                                 float* __restrict__ out){
    __shared__ float fs[LT];
    __shared__ float scl[128], shf[128];
    int tid = threadIdx.x;
    // fin head: part2 is LB rows x 256 cols (512 threads: 2 chunks x 256 rows)
    {
        int m = tid & 255, chunk = tid >> 8;
        float s = 0.f;
        for (int r = chunk*256; r < chunk*256 + 256; ++r)
            s += part2[(size_t)r * 256 + m];
        fs[tid] = s;
        __syncthreads();
        if (tid < 256){
            float t = fs[tid] + fs[256 + tid];
            fs[tid] = t;
        }
        __syncthreads();
        if (tid < 128){
            float s1 = fs[2*tid], s2 = fs[2*tid+1];
            float inv = 1.0f / (float)NPIX;
            float mu = s1 * inv;
            float var = s2 * inv - mu * mu;
            float sc = (1.0f / sqrtf(var + EPS)) * g2[tid];
            scl[tid] = sc;
            shf[tid] = be2[tid] - mu * sc;
        }
        __syncthreads();
    }
    // out layout (b,o,s) == maxp/minp layout (b,o,s): fully coalesced streams
#pragma unroll
    for (int k = 0; k < 4; ++k){
        int gid = blockIdx.x * (LT*4) + k * LT + tid;   // 1048576 total
        int o = (gid >> 10) & 127;
        float sc = scl[o], sh = shf[o];
        float v = (sc >= 0.f) ? maxp[gid] : minp[gid];
        out[gid] = fmaxf(v * sc + sh, 0.f);
    }
}

extern "C" void kernel_launch(void* const* d_in, const int* in_sizes, int n_in,
                              void* d_out, int out_size, void* d_ws, size_t ws_size,
                              hipStream_t stream) {
    const float* xyz = (const float*)d_in[0];
    const float* pts = (const float*)d_in[1];
    const float* W0 = (const float*)d_in[2];
    const float* b0 = (const float*)d_in[3];
    const float* g0 = (const float*)d_in[4];
    const float* be0 = (const float*)d_in[5];
    const float* W1 = (const float*)d_in[6];
    const float* b1 = (const float*)d_in[7];
    const float* g1 = (const float*)d_in[8];
    const float* be1 = (const float*)d_in[9];
    const float* W2 = (const float*)d_in[10];
    const float* b2 = (const float*)d_in[11];
    const float* g2 = (const float*)d_in[12];
    const float* be2 = (const float*)d_in[13];

    char* ws = (char*)d_ws;
    float* newxyz = (float*)(ws + OFF_NEWXYZ);
    float* xyz_n  = (float*)(ws + OFF_XYZN);
    float* pts_n  = (float*)(ws + OFF_PTSN);
    uint4* y0     = (uint4*)(ws + OFF_Y0);
    uint4* y1     = (uint4*)(ws + OFF_Y1);
    float* maxp   = (float*)(ws + OFF_MAXMIN);
    float* minp   = maxp + (size_t)BB * 128 * SS;
    float* part0  = (float*)(ws + OFF_P0);
    float* part1  = (float*)(ws + OFF_P1);
    float* part2  = (float*)(ws + OFF_P2);

    float* out = (float*)d_out;
    float* out_np = out + BB * 3 * SS;

    hipLaunchKernelGGL(fps_kernel, dim3(8 + TBLK), dim3(FT), 0, stream,
                       xyz, pts, newxyz, out, xyz_n, pts_n);
    hipLaunchKernelGGL(l0_kernel, dim3(LB), dim3(LT), 0, stream,
                       xyz, pts_n, xyz_n, newxyz, W0, b0, y0, part0);
    hipLaunchKernelGGL(l1_kernel, dim3(LB), dim3(LT), 0, stream,
                       y0, part0, g0, be0, W1, b1, y1, part1);
    hipLaunchKernelGGL(l2_kernel, dim3(LB), dim3(LT), 0, stream,
                       y1, part1, g1, be1, W2, b2, maxp, minp, part2);
    hipLaunchKernelGGL(out_kernel, dim3(LB), dim3(LT), 0, stream,
                       maxp, minp, part2, g2, be2, out_np);
}

// Round 19
// 1169.366 us; speedup vs baseline: 1.1112x; 1.1112x over previous
//
#include <hip/hip_runtime.h>

#define BB 8
#define NN 8192
#define SS 1024
#define KK 32
#define NPIX (BB*SS*KK)   // 262144
#define R2C 0.04f
#define EPS 1e-5f

#define FT 1024           // fps threads (16 waves)
#define FW (FT/64)        // 16 waves
#define PPT (NN/FT)       // 8 points per thread
#define NCELL 4096        // 16^3 morton cells
#define TBLK 64           // transpose blocks fused into fps launch

typedef float v2f __attribute__((ext_vector_type(2)));

// ---------- ws layout (bytes) ----------
#define OFF_IDX      0u
#define OFF_NEWXYZ   (OFF_IDX + BB*SS*4)
#define OFF_GIDX     (OFF_NEWXYZ + BB*SS*3*4)
#define OFF_XYZN     (OFF_GIDX + BB*SS*KK*4)
#define OFF_PTSN     (OFF_XYZN + BB*NN*3*4)
#define OFF_Y0       (OFF_PTSN + BB*NN*64*4)
#define OFF_Y1       (OFF_Y0 + NPIX*64*2)
#define OFF_MAXMIN   (OFF_Y1 + NPIX*64*2)       // 2 planes of BB*128*SS floats
#define OFF_P0       (OFF_MAXMIN + BB*SS*128*2*4)
#define OFF_P1       (OFF_P0 + 256*128*4)
#define OFF_P2       (OFF_P1 + 256*128*4)

__device__ __forceinline__ unsigned short f2bf(float x){
    unsigned u = __float_as_uint(x);
    unsigned r = (u + 0x7FFFu + ((u >> 16) & 1u)) >> 16;
    return (unsigned short)r;
}
__device__ __forceinline__ float bf2f(unsigned h){
    return __uint_as_float(h << 16);
}
__device__ __forceinline__ float sqdist3(float dx, float dy, float dz){
    // numpy order, no fma contraction: ((dx*dx)+(dy*dy))+(dz*dz)
    return __fadd_rn(__fadd_rn(__fmul_rn(dx,dx), __fmul_rn(dy,dy)), __fmul_rn(dz,dz));
}
__device__ __forceinline__ int spread4(int v){ // bits 0..3 -> 0,3,6,9
    return (v&1) | ((v&2)<<2) | ((v&4)<<4) | ((v&8)<<6);
}

// ---- DPP helpers ----
template<int CTRL>
__device__ __forceinline__ float dppf_max(float v){
    int o = __builtin_amdgcn_update_dpp(__float_as_int(v), __float_as_int(v), CTRL, 0xf, 0xf, false);
    return fmaxf(v, __int_as_float(o));
}
template<int CTRL>
__device__ __forceinline__ float dppf_min(float v){
    int o = __builtin_amdgcn_update_dpp(__float_as_int(v), __float_as_int(v), CTRL, 0xf, 0xf, false);
    return fminf(v, __int_as_float(o));
}
template<int CTRL>
__device__ __forceinline__ unsigned dppu_min(unsigned v){
    unsigned o = (unsigned)__builtin_amdgcn_update_dpp((int)v, (int)v, CTRL, 0xf, 0xf, false);
    return min(v, o);
}
template<int CTRL>
__device__ __forceinline__ float dpp_sum_step(float v){
    int o = __builtin_amdgcn_update_dpp(0, __float_as_int(v), CTRL, 0xf, 0xf, true);
    return v + __int_as_float(o);
}
__device__ __forceinline__ float wave_sum_f32(float v){   // lane63 = sum over 64
    v = dpp_sum_step<0x111>(v); v = dpp_sum_step<0x112>(v);
    v = dpp_sum_step<0x114>(v); v = dpp_sum_step<0x118>(v);
    v = dpp_sum_step<0x142>(v); v = dpp_sum_step<0x143>(v);
    return v;
}
__device__ __forceinline__ float grp32_max(float v){      // lanes 31/63 = group max
    v = dppf_max<0x111>(v); v = dppf_max<0x112>(v);
    v = dppf_max<0x114>(v); v = dppf_max<0x118>(v);
    v = dppf_max<0x142>(v);
    return v;
}
__device__ __forceinline__ float grp32_min(float v){      // lanes 31/63 = group min
    v = dppf_min<0x111>(v); v = dppf_min<0x112>(v);
    v = dppf_min<0x114>(v); v = dppf_min<0x118>(v);
    v = dppf_min<0x142>(v);
    return v;
}
__device__ __forceinline__ float wave_max_f32(float v){   // lane63 = max over 64
    v = dppf_max<0x111>(v); v = dppf_max<0x112>(v);
    v = dppf_max<0x114>(v); v = dppf_max<0x118>(v);
    v = dppf_max<0x142>(v); v = dppf_max<0x143>(v);
    return v;
}
__device__ __forceinline__ unsigned wave_min_u32(unsigned v){ // lane63 = min over 64
    v = dppu_min<0x111>(v); v = dppu_min<0x112>(v);
    v = dppu_min<0x114>(v); v = dppu_min<0x118>(v);
    v = dppu_min<0x142>(v); v = dppu_min<0x143>(v);
    return v;
}

// ---------- FPS (blocks 0..7) + fused transpose (blocks 8..71) ----------
__global__ __launch_bounds__(FT) void fps_kernel(const float* __restrict__ xyz,
                                                 const float* __restrict__ pts,
                                                 float* __restrict__ newxyz,
                                                 float* __restrict__ out,
                                                 float* __restrict__ xyz_n,
                                                 float* __restrict__ pts_n){
    __shared__ float sxyz[NN * 3];               // interleaved x,y,z per point
    __shared__ int   si[NN];                     // sorted -> original idx
    __shared__ int   hist[NCELL];                // sort workspace, then winner history
    __shared__ int   waveTot[FW];
    __shared__ unsigned long long cells[SS];     // one winner cell per iteration
    int tid = threadIdx.x;

    if (blockIdx.x >= 8){
        // transpose path: xyz (B,3,N)->(B,N,3), pts (B,64,N)->(B,N,64)
        int gid = (blockIdx.x - 8) * FT + tid;   // 65536 = B*N
        int b = gid >> 13, i = gid & (NN - 1);
        const float* xb = xyz + (size_t)b * 3 * NN;
        float x = xb[i], y = xb[NN + i], z = xb[2 * NN + i];
        float* xd = xyz_n + ((size_t)b * NN + i) * 3;
        xd[0] = x; xd[1] = y; xd[2] = z;
        const float* pb = pts + (size_t)b * 64 * NN + i;
        float4* pd = (float4*)(pts_n + ((size_t)b * NN + i) * 64);
#pragma unroll
        for (int q = 0; q < 16; ++q){
            float4 v;
            v.x = pb[(q*4+0)*NN]; v.y = pb[(q*4+1)*NN];
            v.z = pb[(q*4+2)*NN]; v.w = pb[(q*4+3)*NN];
            pd[q] = v;
        }
        return;
    }

    int b = blockIdx.x;
    int wave = tid >> 6, lane = tid & 63;
    const float* xb = xyz + (size_t)b * 3 * NN;

    // ---- load coords to LDS + morton cells ----
    int cell[PPT];
#pragma unroll
    for (int j = 0; j < PPT; ++j){
        int i = tid + j * FT;
        float x = xb[i], y = xb[NN + i], z = xb[2*NN + i];
        sxyz[i*3]   = x; sxyz[i*3+1] = y; sxyz[i*3+2] = z;
        int cx = min(15, max(0, (int)(x * 16.f)));
        int cy = min(15, max(0, (int)(y * 16.f)));
        int cz = min(15, max(0, (int)(z * 16.f)));
        cell[j] = spread4(cx) | (spread4(cy) << 1) | (spread4(cz) << 2);
    }
#pragma unroll
    for (int k = 0; k < NCELL/FT; ++k) hist[tid * (NCELL/FT) + k] = 0;
    cells[tid] = 0ull;   // FT == SS == 1024
    __syncthreads();
#pragma unroll
    for (int j = 0; j < PPT; ++j) atomicAdd(&hist[cell[j]], 1);
    __syncthreads();
    // ---- exclusive scan over 4096 cells ----
    {
        int base0 = tid * (NCELL/FT);
        int sum4 = 0;
#pragma unroll
        for (int k = 0; k < NCELL/FT; ++k) sum4 += hist[base0 + k];
        int s = sum4;
#pragma unroll
        for (int m = 1; m < 64; m <<= 1){
            int v = __shfl_up(s, m);
            if (lane >= m) s += v;
        }
        if (lane == 63) waveTot[wave] = s;
        __syncthreads();
        int wbase = 0;
#pragma unroll
        for (int w2 = 0; w2 < FW; ++w2) if (w2 < wave) wbase += waveTot[w2];
        int run = wbase + s - sum4;
#pragma unroll
        for (int k = 0; k < NCELL/FT; ++k){
            int h = hist[base0 + k];
            hist[base0 + k] = run;
            run += h;
        }
    }
    __syncthreads();
#pragma unroll
    for (int j = 0; j < PPT; ++j){
        int pos = atomicAdd(&hist[cell[j]], 1);
        si[pos] = tid + j * FT;
    }
    __syncthreads();
    // ---- gather sorted chunk + bbox (packed v2f regs) ----
    v2f px[PPT/2], py[PPT/2], pz[PPT/2];
    float dist[PPT];
    int oi[PPT];
    float bxmin =  1e30f, bxmax = -1e30f;
    float bymin =  1e30f, bymax = -1e30f;
    float bzmin =  1e30f, bzmax = -1e30f;
#pragma unroll
    for (int j = 0; j < PPT; ++j){
        int g = si[tid * PPT + j];
        oi[j] = g;
        float x = sxyz[g*3], y = sxyz[g*3+1], z = sxyz[g*3+2];
        px[j>>1][j&1] = x; py[j>>1][j&1] = y; pz[j>>1][j&1] = z;
        bxmin = fminf(bxmin, x); bxmax = fmaxf(bxmax, x);
        bymin = fminf(bymin, y); bymax = fmaxf(bymax, y);
        bzmin = fminf(bzmin, z); bzmax = fmaxf(bzmax, z);
        dist[j] = __int_as_float(0x7f800000); // +inf
    }
    __syncthreads();   // hist[] now dead -> reused as winner history

    float tmax = __int_as_float(0x7f800000);
    int   bidx = 0;
    unsigned long long wkey = 0ull;
    int w = 0;
    for (int t = 0; t < SS; ++t){
        if (tid == 0) hist[t] = w;     // reference: idx[t] = CURRENT point
        int w3 = w * 3;
        float lx = sxyz[w3], ly = sxyz[w3+1], lz = sxyz[w3+2];
        float cdx = __fsub_rn(lx, fminf(fmaxf(lx, bxmin), bxmax));
        float cdy = __fsub_rn(ly, fminf(fmaxf(ly, bymin), bymax));
        float cdz = __fsub_rn(lz, fminf(fmaxf(lz, bzmin), bzmax));
        float d_bb = sqdist3(cdx, cdy, cdz);
        bool active = d_bb < tmax;
        unsigned long long bal = __ballot(active);
        if (bal){
            if (active){
                {
#pragma clang fp contract(off)
                    v2f lx2 = {lx, lx}, ly2 = {ly, ly}, lz2 = {lz, lz};
#pragma unroll
                    for (int p = 0; p < PPT/2; ++p){
                        v2f dx = px[p] - lx2;
                        v2f dy = py[p] - ly2;
                        v2f dz = pz[p] - lz2;
                        v2f d  = ((dx*dx) + (dy*dy)) + (dz*dz);  // numpy order
                        dist[2*p]   = fminf(dist[2*p],   d[0]);
                        dist[2*p+1] = fminf(dist[2*p+1], d[1]);
                    }
                }
                float m0 = fmaxf(dist[0], dist[1]);
                float m1 = fmaxf(dist[2], dist[3]);
                float m2 = fmaxf(dist[4], dist[5]);
                float m3 = fmaxf(dist[6], dist[7]);
                m0 = fmaxf(m0, m1); m2 = fmaxf(m2, m3);
                float maxd = fmaxf(m0, m2);
                int bo = 0x7fffffff;
#pragma unroll
                for (int j = 0; j < PPT; ++j)
                    if (dist[j] == maxd) bo = min(bo, oi[j]);
                tmax = maxd; bidx = bo;
            }
            // two-phase reduce: f32 max, then u32 min-index among maxima
            float m = wave_max_f32(tmax);
            float sm = __int_as_float(__builtin_amdgcn_readlane(__float_as_int(m), 63));
            unsigned cand = (tmax == sm) ? (unsigned)bidx : 0xFFFFFFFFu;
            cand = wave_min_u32(cand);
            unsigned sidx = (unsigned)__builtin_amdgcn_readlane((int)cand, 63);
            wkey = ((unsigned long long)__float_as_uint(sm) << 32) | (unsigned)(~sidx);
        }
        if (lane == 63) atomicMax(&cells[t], wkey);
        __syncthreads();
        w = (int)(~(unsigned)cells[t]);
    }
    __syncthreads();
    // ---- coalesced writeback from history ----
    for (int t2 = tid; t2 < SS; t2 += FT){
        int hw = hist[t2] * 3;
        float x = sxyz[hw], y = sxyz[hw+1], z = sxyz[hw+2];
        out[(size_t)b * 3 * SS + t2]          = x;
        out[(size_t)b * 3 * SS + SS + t2]     = y;
        out[(size_t)b * 3 * SS + 2*SS + t2]   = z;
        float* nw = newxyz + ((size_t)b * SS + t2) * 3;
        nw[0] = x; nw[1] = y; nw[2] = z;
    }
}

// ---------- layer0: in-block ball query + gather(streamed) + 67->64 matmul + stats ----------
__global__ __launch_bounds__(1024) void l0_kernel(const float* __restrict__ xyz,
                                                  const float* __restrict__ pts_n,
                                                  const float* __restrict__ xyz_n,
                                                  const float* __restrict__ newxyz,
                                                  const float* __restrict__ W0,
                                                  const float* __restrict__ b0,
                                                  uint4* __restrict__ y0,
                                                  float* __restrict__ part0){
    __shared__ float lsum[16][64][2];   // 8 KB
    __shared__ int   gq[32][KK];        // 4 KB: this block's 32 samples
    int tid = threadIdx.x;
    int pixel = blockIdx.x * 1024 + tid;    // 256 blocks
    int sample = pixel >> 5;
    int b = sample >> 10;                   // == blockIdx.x >> 5
    int wave = tid >> 6, lane = tid & 63;

    // ---- phase A: ball query for this block's 32 samples (wave w -> samples 2w, 2w+1) ----
    {
        const float* xb = xyz + (size_t)b * 3 * NN;
#pragma unroll
        for (int s2 = 0; s2 < 2; ++s2){
            int ls = wave * 2 + s2;                    // local sample 0..31
            int smp = blockIdx.x * 32 + ls;
            const float* nw = newxyz + (size_t)smp * 3;
            float cx = nw[0], cy = nw[1], cz = nw[2];
            int total = 0, firstIdx = -1;
            for (int base = 0; base < NN; base += 64){
                int i = base + lane;
                float dx = __fsub_rn(cx, xb[i]);
                float dy = __fsub_rn(cy, xb[NN + i]);
                float dz = __fsub_rn(cz, xb[2*NN + i]);
                float d2 = sqdist3(dx, dy, dz);
                bool in = (d2 <= R2C);
                unsigned long long m = __ballot(in);
                int pos = total + __popcll(m & ((1ull << lane) - 1ull));
                if (in && pos < KK) gq[ls][pos] = i;
                if (firstIdx < 0 && m) firstIdx = base + (__ffsll((unsigned long long)m) - 1);
                total += __popcll(m);
                if (total >= KK) break;
            }
            if (total < KK){
                int f = (total > 0) ? firstIdx : (NN - 1);
                for (int p = total + lane; p < KK; p += 64) gq[ls][p] = f;
            }
        }
    }
    __syncthreads();

    // ---- phase B: gather + streamed matmul + stats ----
    int gi = gq[tid >> 5][tid & 31];
    float acc[64];
#pragma unroll
    for (int j = 0; j < 64; ++j) acc[j] = b0[j];
    {
        const float4* prow = (const float4*)(pts_n + ((size_t)b * NN + gi) * 64);
#pragma unroll
        for (int q = 0; q < 16; ++q){
            float4 v = prow[q];
            int c = q * 4;
#pragma unroll
            for (int j = 0; j < 64; ++j){
                acc[j] += v.x * W0[j*67 + c];
                acc[j] += v.y * W0[j*67 + c+1];
                acc[j] += v.z * W0[j*67 + c+2];
                acc[j] += v.w * W0[j*67 + c+3];
            }
        }
        const float* pr = xyz_n + ((size_t)b * NN + gi) * 3;
        const float* nw = newxyz + (size_t)sample * 3;
#pragma unroll
        for (int k = 0; k < 3; ++k){
            float fe = __fsub_rn(pr[k], nw[k]) / 0.2f;
#pragma unroll
            for (int j = 0; j < 64; ++j) acc[j] += fe * W0[j*67 + 64 + k];
        }
    }
#pragma unroll
    for (int j = 0; j < 64; ++j){
        float v = acc[j];
        float s1 = wave_sum_f32(v);
        float s2 = wave_sum_f32(v * v);
        if (lane == 63){ lsum[wave][j][0] = s1; lsum[wave][j][1] = s2; }
    }
    // pack + store
    uint4* yo = y0 + (size_t)pixel * 8;
#pragma unroll
    for (int oc = 0; oc < 8; ++oc){
        uint4 pk;
        pk.x = f2bf(acc[oc*8+0]) | ((unsigned)f2bf(acc[oc*8+1]) << 16);
        pk.y = f2bf(acc[oc*8+2]) | ((unsigned)f2bf(acc[oc*8+3]) << 16);
        pk.z = f2bf(acc[oc*8+4]) | ((unsigned)f2bf(acc[oc*8+5]) << 16);
        pk.w = f2bf(acc[oc*8+6]) | ((unsigned)f2bf(acc[oc*8+7]) << 16);
        yo[oc] = pk;
    }
    __syncthreads();
    if (tid < 128){
        float s = 0.f;
#pragma unroll
        for (int w2 = 0; w2 < 16; ++w2) s += lsum[w2][tid>>1][tid&1];
        part0[(size_t)blockIdx.x * 128 + tid] = s;
    }
}

// ---------- redundant per-block BN finalize (deterministic, from 256x128 partials) ----------
__device__ __forceinline__ void fin_head128(const float* __restrict__ part,
                                            const float* __restrict__ g,
                                            const float* __restrict__ be,
                                            float* fs, float* scl, float* shf){
    int tid = threadIdx.x;               // 1024
    int m = tid & 127, chunk = tid >> 7; // 8 chunks x 32 rows
    float s = 0.f;
    for (int r = chunk*32; r < chunk*32 + 32; ++r)
        s += part[(size_t)r * 128 + m];
    fs[tid] = s;
    __syncthreads();
    if (tid < 128){
        float t = fs[tid];
#pragma unroll
        for (int c = 1; c < 8; ++c) t += fs[c*128 + tid];
        fs[tid] = t;
    }
    __syncthreads();
    if (tid < 64){
        float s1 = fs[2*tid], s2 = fs[2*tid+1];
        float inv = 1.0f / (float)NPIX;
        float mu = s1 * inv;
        float var = s2 * inv - mu * mu;
        float sc = (1.0f / sqrtf(var + EPS)) * g[tid];
        scl[tid] = sc;
        shf[tid] = be[tid] - mu * sc;
    }
    __syncthreads();
}

// ---------- layer1: fin0 head + bn+relu + 64->64 matmul + stats ----------
__global__ __launch_bounds__(1024) void l1_kernel(const uint4* __restrict__ y0,
                                                  const float* __restrict__ part0,
                                                  const float* __restrict__ g0,
                                                  const float* __restrict__ be0,
                                                  const float* __restrict__ W1,
                                                  const float* __restrict__ b1,
                                                  uint4* __restrict__ y1,
                                                  float* __restrict__ part1){
    __shared__ float lsum[16][64][2];   // 8 KB
    __shared__ float fs[1024];          // 4 KB
    __shared__ float scl[64], shf[64];
    int tid = threadIdx.x;
    int pixel = blockIdx.x * 1024 + tid;
    int wave = tid >> 6, lane = tid & 63;

    fin_head128(part0, g0, be0, fs, scl, shf);

    float x[64];
#pragma unroll
    for (int q = 0; q < 8; ++q){
        uint4 v = y0[(size_t)pixel * 8 + q];
        unsigned wv[4] = {v.x, v.y, v.z, v.w};
#pragma unroll
        for (int r = 0; r < 4; ++r){
            int c = q*8 + r*2;
            x[c]   = fmaxf(bf2f(wv[r] & 0xFFFFu) * scl[c]   + shf[c],   0.f);
            x[c+1] = fmaxf(bf2f(wv[r] >> 16)     * scl[c+1] + shf[c+1], 0.f);
        }
    }
#pragma unroll
    for (int oc = 0; oc < 8; ++oc){
        float acc[8];
#pragma unroll
        for (int j = 0; j < 8; ++j) acc[j] = b1[oc*8+j];
#pragma unroll
        for (int c = 0; c < 64; ++c){
            float fe = x[c];
#pragma unroll
            for (int j = 0; j < 8; ++j) acc[j] += fe * W1[(oc*8+j)*64 + c];
        }
        uint4 pk;
        unsigned us[8];
#pragma unroll
        for (int j = 0; j < 8; ++j){
            float v = acc[j];
            float s1 = wave_sum_f32(v);
            float s2 = wave_sum_f32(v * v);
            if (lane == 63){ lsum[wave][oc*8+j][0] = s1; lsum[wave][oc*8+j][1] = s2; }
            us[j] = f2bf(v);
        }
        pk.x = us[0] | (us[1] << 16);
        pk.y = us[2] | (us[3] << 16);
        pk.z = us[4] | (us[5] << 16);
        pk.w = us[6] | (us[7] << 16);
        y1[(size_t)pixel * 8 + oc] = pk;
    }
    __syncthreads();
    if (tid < 128){
        float s = 0.f;
#pragma unroll
        for (int w2 = 0; w2 < 16; ++w2) s += lsum[w2][tid>>1][tid&1];
        part1[(size_t)blockIdx.x * 128 + tid] = s;
    }
}

// ---------- layer2: fin1 head + bn+relu + 64->128 matmul + k-max/min + stats ----------
__global__ __launch_bounds__(1024) void l2_kernel(const uint4* __restrict__ y1,
                                                  const float* __restrict__ part1,
                                                  const float* __restrict__ g1,
                                                  const float* __restrict__ be1,
                                                  const float* __restrict__ W2,
                                                  const float* __restrict__ b2,
                                                  float* __restrict__ maxp,
                                                  float* __restrict__ minp,
                                                  float* __restrict__ part2){
    __shared__ float lsum[16][128][2];  // 16 KB
    __shared__ float fs[1024];
    __shared__ float scl[64], shf[64];
    int tid = threadIdx.x;
    int pixel = blockIdx.x * 1024 + tid;
    int sample = pixel >> 5;
    int sb = sample >> 10;              // batch
    int sl = sample & 1023;             // sample within batch
    int wave = tid >> 6, lane = tid & 63;

    fin_head128(part1, g1, be1, fs, scl, shf);

    float x[64];
#pragma unroll
    for (int q = 0; q < 8; ++q){
        uint4 v = y1[(size_t)pixel * 8 + q];
        unsigned wv[4] = {v.x, v.y, v.z, v.w};
#pragma unroll
        for (int r = 0; r < 4; ++r){
            int c = q*8 + r*2;
            x[c]   = fmaxf(bf2f(wv[r] & 0xFFFFu) * scl[c]   + shf[c],   0.f);
            x[c+1] = fmaxf(bf2f(wv[r] >> 16)     * scl[c+1] + shf[c+1], 0.f);
        }
    }
#pragma unroll
    for (int oc = 0; oc < 16; ++oc){
        float acc[8];
#pragma unroll
        for (int j = 0; j < 8; ++j) acc[j] = b2[oc*8+j];
#pragma unroll
        for (int c = 0; c < 64; ++c){
            float fe = x[c];
#pragma unroll
            for (int j = 0; j < 8; ++j) acc[j] += fe * W2[(oc*8+j)*64 + c];
        }
#pragma unroll
        for (int j = 0; j < 8; ++j){
            float v = acc[j];
            int ch = oc*8 + j;
            float mx = grp32_max(v);
            float mn = grp32_min(v);
            float s1 = wave_sum_f32(v);
            float s2 = wave_sum_f32(v * v);
            if (lane == 63){ lsum[wave][ch][0] = s1; lsum[wave][ch][1] = s2; }
            if ((tid & 31) == 31){
                size_t idx = ((size_t)sb * 128 + ch) * 1024 + sl;
                maxp[idx] = mx; minp[idx] = mn;
            }
        }
    }
    __syncthreads();
    if (tid < 256){
        float s = 0.f;
#pragma unroll
        for (int w2 = 0; w2 < 16; ++w2) s += lsum[w2][tid>>1][tid&1];
        part2[(size_t)blockIdx.x * 256 + tid] = s;
    }
}

// ---------- output: fin2 head + apply BN to max/min, relu, coalesced write ----------
__global__ __launch_bounds__(1024) void out_kernel(const float* __restrict__ maxp,
                                                   const float* __restrict__ minp,
                                                   const float* __restrict__ part2,
                                                   const float* __restrict__ g2,
                                                   const float* __restrict__ be2,
                                                   float* __restrict__ out){
    __shared__ float fs[1024];
    __shared__ float scl[128], shf[128];
    int tid = threadIdx.x;
    // fin head: part2 is 256 rows x 256 cols
    {
        int m = tid & 255, chunk = tid >> 8;   // 4 chunks x 64 rows
        float s = 0.f;
        for (int r = chunk*64; r < chunk*64 + 64; ++r)
            s += part2[(size_t)r * 256 + m];
        fs[tid] = s;
        __syncthreads();
        if (tid < 256){
            float t = fs[tid] + fs[256 + tid] + fs[512 + tid] + fs[768 + tid];
            fs[tid] = t;
        }
        __syncthreads();
        if (tid < 128){
            float s1 = fs[2*tid], s2 = fs[2*tid+1];
            float inv = 1.0f / (float)NPIX;
            float mu = s1 * inv;
            float var = s2 * inv - mu * mu;
            float sc = (1.0f / sqrtf(var + EPS)) * g2[tid];
            scl[tid] = sc;
            shf[tid] = be2[tid] - mu * sc;
        }
        __syncthreads();
    }
    // out layout (b,o,s) == maxp/minp layout (b,o,s): fully coalesced streams
#pragma unroll
    for (int k = 0; k < 4; ++k){
        int gid = blockIdx.x * 4096 + k * 1024 + tid;   // 1048576 total
        int o = (gid >> 10) & 127;
        float sc = scl[o], sh = shf[o];
        float v = (sc >= 0.f) ? maxp[gid] : minp[gid];
        out[gid] = fmaxf(v * sc + sh, 0.f);
    }
}

extern "C" void kernel_launch(void* const* d_in, const int* in_sizes, int n_in,
                              void* d_out, int out_size, void* d_ws, size_t ws_size,
                              hipStream_t stream) {
    const float* xyz = (const float*)d_in[0];
    const float* pts = (const float*)d_in[1];
    const float* W0 = (const float*)d_in[2];
    const float* b0 = (const float*)d_in[3];
    const float* g0 = (const float*)d_in[4];
    const float* be0 = (const float*)d_in[5];
    const float* W1 = (const float*)d_in[6];
    const float* b1 = (const float*)d_in[7];
    const float* g1 = (const float*)d_in[8];
    const float* be1 = (const float*)d_in[9];
    const float* W2 = (const float*)d_in[10];
    const float* b2 = (const float*)d_in[11];
    const float* g2 = (const float*)d_in[12];
    const float* be2 = (const float*)d_in[13];

    char* ws = (char*)d_ws;
    float* newxyz = (float*)(ws + OFF_NEWXYZ);
    float* xyz_n  = (float*)(ws + OFF_XYZN);
    float* pts_n  = (float*)(ws + OFF_PTSN);
    uint4* y0     = (uint4*)(ws + OFF_Y0);
    uint4* y1     = (uint4*)(ws + OFF_Y1);
    float* maxp   = (float*)(ws + OFF_MAXMIN);
    float* minp   = maxp + (size_t)BB * 128 * SS;
    float* part0  = (float*)(ws + OFF_P0);
    float* part1  = (float*)(ws + OFF_P1);
    float* part2  = (float*)(ws + OFF_P2);

    float* out = (float*)d_out;
    float* out_np = out + BB * 3 * SS;

    hipLaunchKernelGGL(fps_kernel, dim3(8 + TBLK), dim3(FT), 0, stream,
                       xyz, pts, newxyz, out, xyz_n, pts_n);
    hipLaunchKernelGGL(l0_kernel, dim3(256), dim3(1024), 0, stream,
                       xyz, pts_n, xyz_n, newxyz, W0, b0, y0, part0);
    hipLaunchKernelGGL(l1_kernel, dim3(256), dim3(1024), 0, stream,
                       y0, part0, g0, be0, W1, b1, y1, part1);
    hipLaunchKernelGGL(l2_kernel, dim3(256), dim3(1024), 0, stream,
                       y1, part1, g1, be1, W2, b2, maxp, minp, part2);
    hipLaunchKernelGGL(out_kernel, dim3(256), dim3(1024), 0, stream,
                       maxp, minp, part2, g2, be2, out_np);
}